// Round 3
// baseline (2047.296 us; speedup 1.0000x reference)
//
#include <hip/hip_runtime.h>
#include <cstdint>

#define TT 1024
#define BB 512
#define KK 128
#define XPAD 132   // LDS row stride in floats: bank shift 4/row -> <=2-way aliasing
#define NSLOT 8

typedef __attribute__((ext_vector_type(8))) short short8;
typedef __attribute__((ext_vector_type(4))) float f4;
typedef __attribute__((ext_vector_type(4))) unsigned int uint4v;

__device__ __forceinline__ unsigned short f2bf_rtne(float x) {
  unsigned u = __float_as_uint(x);
  u += 0x7FFF + ((u >> 16) & 1);
  return (unsigned short)(u >> 16);
}

// pack trunc-bf16(l) into low16, trunc-bf16(h) into high16 — one v_perm_b32
__device__ __forceinline__ unsigned pack_trunc(float l, float h) {
  return __builtin_amdgcn_perm(__float_as_uint(h), __float_as_uint(l), 0x07060302u);
}

// barrier waiting only on LDS (lgkmcnt=0); global prefetch stays in flight
__device__ __forceinline__ void lgkm_barrier() {
  __atomic_signal_fence(__ATOMIC_SEQ_CST);
  __builtin_amdgcn_s_waitcnt(0xC07F);  // vmcnt=63, expcnt=7, lgkmcnt=0
  __builtin_amdgcn_s_barrier();
  __atomic_signal_fence(__ATOMIC_SEQ_CST);
}

// ---------------------------------------------------------------------------
// 3-wave fused forward. grid = 32 blocks x 192 threads.
//   wave 0 (consumer): serial recurrence, register-resident. Per group of 4
//     steps: preload 4 X-tiles + masks from the LDS ring (one amortized
//     lgkm wait), then 4x {32 MFMA + mul + select + pack}. No global loads,
//     no exp on the chain. First MFMA of each chain uses C=0 (no acc zeroing).
//   wave 1 (producer): loads em 4..8 steps ahead (static 4-buffer reg ring),
//     computes X=exp(em), writes X+mask into the 8-slot LDS ring.
//   wave 2 (path): gold-path score + boundary terms for the block's 16 rows,
//     4 t per group (paced by the same barriers; em gathers are L2-hot since
//     the producer streamed those lines 1-2 groups earlier).
// Sync: one lgkm-only barrier per group (vmcnt loads stay in flight). All
// three waves execute exactly 257 s_barriers.
//
// Recurrence layout: one wave owns 16 batch rows x 128 states; k-mapping
// c_k(kt, 8q+j) = 32kt + 16(j>>2) + 4q + (j&3) makes the packed bf16
// accumulator pairs exactly the next step's B-frags in-lane. Renorm every 4
// steps (power-of-2 scale folded into the group's first X-tile, base +=
// k*ln2); masked rows carry old fp32 state exactly. Dummy step t=1024 has
// mask forced 0 (pure carry).
// ---------------------------------------------------------------------------
__global__ __launch_bounds__(192, 1) void crf_forward(
    const float* __restrict__ em, const float* __restrict__ mask,
    const float* __restrict__ start_t, const float* __restrict__ trans,
    const float* __restrict__ end_t, const int* __restrict__ tags,
    float* __restrict__ logz, float* __restrict__ ws_path)
{
  const int tid  = threadIdx.x;
  const int wid  = tid >> 6;     // 0 consumer, 1 producer, 2 path
  const int lane = tid & 63;
  const int q    = lane >> 4;    // 0..3
  const int lo   = lane & 15;    // batch row within block
  const int b0   = blockIdx.x * 16;

  __shared__ __align__(16) float Xs[NSLOT][16][XPAD];   // X ring; mask at col 128

  const size_t TS = (size_t)BB * KK;
  const float* emlane = em + (size_t)(b0 + lo) * KK + 4 * q;  // + t*TS + 16*mt
  const float* mrow   = mask + (b0 + lo);                     // + t*BB

  // ---- consumer persistent state
  short8 Af[8][4];
  f4 S[8];
  uint4v PB[4];
  float base = 0.f, mvPrev = 1.0f;

  // ---- producer reg ring (static names — rule #20)
  f4 LA[8], LB[8], LC[8], LD[8];
  float mA = 0.f, mB = 0.f, mC = 0.f, mD = 0.f;

  // ---- path-wave persistent state: lane (lo,q) owns t = 4g+q for row b0+lo
  float pacc = 0.f, msum = 0.f, mkP = 0.f;
  int tgC = 0, tpC = 0;

  if (wid == 0) {
    // E fragments, permuted k-mapping: Af[mt][kt][j] = exp(E)[c_k][c_m]
#pragma unroll
    for (int mt = 0; mt < 8; ++mt)
#pragma unroll
      for (int kt = 0; kt < 4; ++kt) {
        short8 v;
#pragma unroll
        for (int j = 0; j < 8; ++j) {
          const int ck = 32 * kt + 16 * (j >> 2) + 4 * q + (j & 3);
          v[j] = (short)f2bf_rtne(__expf(trans[(size_t)ck * KK + 16 * mt + lo]));
        }
        Af[mt][kt] = v;
      }
    // P(0) = exp(start + em(0))
#pragma unroll
    for (int mt = 0; mt < 8; ++mt) {
      const f4 e0 = *(const f4*)(emlane + 16 * mt);
      const f4 st = *(const f4*)(start_t + 16 * mt + 4 * q);
#pragma unroll
      for (int i = 0; i < 4; ++i) S[mt][i] = __expf(st[i] + e0[i]);
    }
#pragma unroll
    for (int kt = 0; kt < 4; ++kt) {
      PB[kt][0] = pack_trunc(S[2 * kt][0],     S[2 * kt][1]);
      PB[kt][1] = pack_trunc(S[2 * kt][2],     S[2 * kt][3]);
      PB[kt][2] = pack_trunc(S[2 * kt + 1][0], S[2 * kt + 1][1]);
      PB[kt][3] = pack_trunc(S[2 * kt + 1][2], S[2 * kt + 1][3]);
    }
  } else if (wid == 1) {
    // producer prologue loads for t = 1..4
#pragma unroll
    for (int mt = 0; mt < 8; ++mt) {
      LA[mt] = *(const f4*)(emlane + 1 * TS + 16 * mt);
      LB[mt] = *(const f4*)(emlane + 2 * TS + 16 * mt);
      LC[mt] = *(const f4*)(emlane + 3 * TS + 16 * mt);
      LD[mt] = *(const f4*)(emlane + 4 * TS + 16 * mt);
    }
    mA = mrow[1 * BB]; mB = mrow[2 * BB]; mC = mrow[3 * BB]; mD = mrow[4 * BB];
  } else {
    // path prologue: tags/mask for g=0 (t = q)
    const int rowg = b0 + lo;
    tgC = tags[q * BB + rowg];
    tpC = (q >= 1) ? tags[(q - 1) * BB + rowg] : 0;
    mkP = mask[q * BB + rowg];
  }

  // produce X(t) into slot t&7 from buffer Ls, then issue loads for t+4
  auto PROD = [&](const int t, f4 (&Ls)[8], float& ms) {
    if (t > TT) return;                       // t in [1..1024]
    float* xb = &Xs[t & 7][lo][0];
#pragma unroll
    for (int mt = 0; mt < 8; ++mt) {
      f4 x;
#pragma unroll
      for (int i = 0; i < 4; ++i) x[i] = __expf(Ls[mt][i]);
      *(f4*)(xb + 16 * mt + 4 * q) = x;
    }
    if (q == 0) xb[128] = (t <= TT - 1) ? ms : 0.f;   // dummy step: mask 0
    const int tp = (t + 4 <= TT - 1) ? (t + 4) : (TT - 1);
#pragma unroll
    for (int mt = 0; mt < 8; ++mt)
      Ls[mt] = *(const f4*)(emlane + (size_t)tp * TS + 16 * mt);
    ms = mrow[(size_t)tp * BB];
  };

  // one recurrence step from preloaded X regs
  auto CONS = [&](const f4 (&X)[8], const float mk, const bool scb,
                  const float kln2, const bool rn) {
    short8 Bf[4];
#pragma unroll
    for (int kt = 0; kt < 4; ++kt) Bf[kt] = __builtin_bit_cast(short8, PB[kt]);

    f4 acc[8];
#pragma unroll
    for (int mt = 0; mt < 8; ++mt)
      acc[mt] = __builtin_amdgcn_mfma_f32_16x16x32_bf16(
          Af[mt][0], Bf[0], f4{0.f, 0.f, 0.f, 0.f}, 0, 0, 0);
#pragma unroll
    for (int kt = 1; kt < 4; ++kt)
#pragma unroll
      for (int mt = 0; mt < 8; ++mt)
        acc[mt] = __builtin_amdgcn_mfma_f32_16x16x32_bf16(Af[mt][kt], Bf[kt], acc[mt], 0, 0, 0);

    const bool upd = (mk != 0.f);
#pragma unroll
    for (int mt = 0; mt < 8; ++mt) {
      const f4 n = acc[mt] * X[mt];           // vector form -> v_pk_mul_f32
#pragma unroll
      for (int i = 0; i < 4; ++i) S[mt][i] = upd ? n[i] : S[mt][i];
    }
    if (scb && upd) base += kln2;

#pragma unroll
    for (int kt = 0; kt < 4; ++kt) {
      PB[kt][0] = pack_trunc(S[2 * kt][0],     S[2 * kt][1]);
      PB[kt][1] = pack_trunc(S[2 * kt][2],     S[2 * kt][3]);
      PB[kt][2] = pack_trunc(S[2 * kt + 1][0], S[2 * kt + 1][1]);
      PB[kt][3] = pack_trunc(S[2 * kt + 1][2], S[2 * kt + 1][3]);
    }

    if (rn) {
      float mv = fmaxf(fmaxf(S[0][0], S[0][1]), fmaxf(S[0][2], S[0][3]));
#pragma unroll
      for (int mt = 1; mt < 8; ++mt)
        mv = fmaxf(mv, fmaxf(fmaxf(S[mt][0], S[mt][1]), fmaxf(S[mt][2], S[mt][3])));
      mv = fmaxf(mv, __shfl_xor(mv, 16));
      mv = fmaxf(mv, __shfl_xor(mv, 32));
      mvPrev = mv;
    }
  };

  // producer prologue: fill slots 1..4, issue loads t=5..8
  if (wid == 1) { PROD(1, LA, mA); PROD(2, LB, mB); PROD(3, LC, mC); PROD(4, LD, mD); }
  lgkm_barrier();   // barrier #1 (all 3 waves)

  for (int g = 0; g < 256; ++g) {
    if (wid == 0) {
      const int t0 = 4 * g;
      float ps = 1.f, kln2 = 0.f;
      const bool sc = (g >= 1);               // scale at t = 4g+1, g>=1
      if (sc) {
        const int k = (int)(__float_as_uint(mvPrev) >> 23) - 127;
        ps = __uint_as_float((unsigned)(127 - k) << 23);
        kln2 = (float)k * 0.6931471805599453f;
      }
      // preload the whole group's X tiles + masks (one amortized lgkm wait)
      f4 XA[8], XB[8], XC[8], XD[8];
      const float* x1 = &Xs[(t0 + 1) & 7][lo][0];
      const float* x2 = &Xs[(t0 + 2) & 7][lo][0];
      const float* x3 = &Xs[(t0 + 3) & 7][lo][0];
      const float* x4 = &Xs[(t0 + 4) & 7][lo][0];
#pragma unroll
      for (int mt = 0; mt < 8; ++mt) {
        XA[mt] = *(const f4*)(x1 + 16 * mt + 4 * q);
        XB[mt] = *(const f4*)(x2 + 16 * mt + 4 * q);
        XC[mt] = *(const f4*)(x3 + 16 * mt + 4 * q);
        XD[mt] = *(const f4*)(x4 + 16 * mt + 4 * q);
      }
      const float mk1 = x1[128], mk2 = x2[128], mk3 = x3[128], mk4 = x4[128];
      if (sc) {
#pragma unroll
        for (int mt = 0; mt < 8; ++mt) XA[mt] *= ps;   // fold scale into X
      }
      CONS(XA, mk1, sc, kln2, false);
      CONS(XB, mk2, false, 0.f, false);
      CONS(XC, mk3, false, 0.f, false);
      CONS(XD, mk4, false, 0.f, true);
    } else if (wid == 1) {
      const int t0 = 4 * g;
      PROD(t0 + 5, LA, mA); PROD(t0 + 6, LB, mB);
      PROD(t0 + 7, LC, mC); PROD(t0 + 8, LD, mD);
    } else {
      const int t    = 4 * g + q;
      const int rowg = b0 + lo;
      int tgN = 0, tpN = 0; float mkN = 0.f;
      if (g + 1 < 256) {                      // prefetch next group's tags/mask
        const int tn = t + 4;
        tgN = tags[tn * BB + rowg];
        tpN = tags[(tn - 1) * BB + rowg];
        mkN = mask[tn * BB + rowg];
      }
      const float ev   = em[((size_t)t * BB + rowg) * KK + tgC];
      const float tv   = trans[(size_t)tpC * KK + tgC];
      const float tsel = (t > 0) ? mkP : 0.f;
      pacc += ev * mkP + tv * tsel;
      msum += mkP;
      tgC = tgN; tpC = tpN; mkP = mkN;
    }
    lgkm_barrier();
  }

  // ---- finales
  if (wid == 0) {
    float s = 0.f;
#pragma unroll
    for (int mt = 0; mt < 8; ++mt) {
      const f4 ed = *(const f4*)(end_t + 16 * mt + 4 * q);
#pragma unroll
      for (int i = 0; i < 4; ++i) s += S[mt][i] * __expf(ed[i]);
    }
    s += __shfl_xor(s, 16);
    s += __shfl_xor(s, 32);
    if (q == 0) logz[b0 + lo] = base + logf(s);
  } else if (wid == 2) {
    float pa = pacc + __shfl_xor(pacc, 16); pa += __shfl_xor(pa, 32);
    float mz = msum + __shfl_xor(msum, 16); mz += __shfl_xor(mz, 32);
    if (q == 0) {
      const int rowg = b0 + lo;
      const int last = (int)(mz + 0.5f) - 1;
      ws_path[rowg] = pa + start_t[tags[rowg]] +
                      end_t[tags[(size_t)last * BB + rowg]];
    }
  }
}

// out = sum_b (ws_path - logz)
__global__ __launch_bounds__(512) void crf_final(
    const float* __restrict__ ws_path, const float* __restrict__ ws_lz,
    float* __restrict__ out)
{
  const int tid = threadIdx.x;
  float v = ws_path[tid] - ws_lz[tid];
  __shared__ float red[8];
#pragma unroll
  for (int off = 32; off; off >>= 1) v += __shfl_xor(v, off);
  if ((tid & 63) == 0) red[tid >> 6] = v;
  __syncthreads();
  if (tid == 0) {
    float s = 0.f;
#pragma unroll
    for (int i = 0; i < 8; ++i) s += red[i];
    out[0] = s;
  }
}

extern "C" void kernel_launch(void* const* d_in, const int* in_sizes, int n_in,
                              void* d_out, int out_size, void* d_ws, size_t ws_size,
                              hipStream_t stream) {
  (void)in_sizes; (void)n_in; (void)out_size; (void)ws_size;
  const float* em    = (const float*)d_in[0];
  const int*   tags  = (const int*)  d_in[1];
  const float* mask  = (const float*)d_in[2];
  const float* st    = (const float*)d_in[3];
  const float* trans = (const float*)d_in[4];
  const float* et    = (const float*)d_in[5];
  float* out = (float*)d_out;

  float* ws_path = (float*)d_ws;     // [512]
  float* ws_lz   = ws_path + 512;    // [512]

  crf_forward<<<32, 192, 0, stream>>>(em, mask, st, trans, et, tags, ws_lz, ws_path);
  crf_final  <<<1, 512, 0, stream>>>(ws_path, ws_lz, out);
}

// Round 6
// 1040.462 us; speedup vs baseline: 1.9677x; 1.9677x over previous
//
#include <hip/hip_runtime.h>
#include <cstdint>

#define TT 1024
#define BB 512
#define KK 128
#define XPAD 132   // LDS row stride in floats
#define NSLOT 8

typedef __attribute__((ext_vector_type(8))) short short8;
typedef __attribute__((ext_vector_type(4))) float f4;
typedef __attribute__((ext_vector_type(4))) unsigned int uint4v;

__device__ __forceinline__ unsigned short f2bf_rtne(float x) {
  unsigned u = __float_as_uint(x);
  u += 0x7FFF + ((u >> 16) & 1);
  return (unsigned short)(u >> 16);
}

// pack trunc-bf16(l) into low16, trunc-bf16(h) into high16 — one v_perm_b32
__device__ __forceinline__ unsigned pack_trunc(float l, float h) {
  return __builtin_amdgcn_perm(__float_as_uint(h), __float_as_uint(l), 0x07060302u);
}

// barrier waiting only on LDS (lgkmcnt=0); global prefetch stays in flight
__device__ __forceinline__ void lgkm_barrier() {
  __atomic_signal_fence(__ATOMIC_SEQ_CST);
  __builtin_amdgcn_s_waitcnt(0xC07F);  // vmcnt=63, expcnt=7, lgkmcnt=0
  __builtin_amdgcn_s_barrier();
  __atomic_signal_fence(__ATOMIC_SEQ_CST);
}

// ---------------------------------------------------------------------------
// 3-wave forward: r2's verified producer/consumer structure with EXACTLY ONE
// change — X-production split across TWO producer waves (column halves).
// grid = 32 blocks x 192 threads.
//   wave 0 (consumer): serial recurrence, register-resident (r2 verbatim).
//     Per step: 8 ds_read_b128 + 32 MFMA + mul/select/pack. No global loads,
//     no exp on the chain.
//   wave 1 (producer-lo): X = exp(em) for mt 0-3 + the mask word.
//   wave 2 (producer-hi): X = exp(em) for mt 4-7.
//     A/B theory: r2 was producer-bound (32 v_exp_f32 wave-instrs + 8
//     ds_write_b128 per step on one wave at ~1/4-rate transcendentals).
//     Each producer now does 16 exps + 4 ds_write_b128 + 4 load-issues.
// Sync: one lgkm-only barrier per 4-step group (vmcnt stays in flight).
// Slot parity: consumer reads slots {4g+1..4g+4}&7 while producers write
// {4g+5..4g+8}&7 — disjoint halves. All waves hit exactly 257 barriers.
//
// Recurrence layout: one wave owns 16 batch rows x 128 states; k-mapping
// c_k(kt, 8q+j) = 32kt + 16(j>>2) + 4q + (j&3) makes the packed bf16
// accumulator pairs exactly the next step's B-frags in-lane. Renorm every 4
// steps (power-of-2 scale, base += k*ln2); masked rows carry old fp32 state
// exactly. Dummy step t=1024 has mask forced 0 (pure carry).
// ---------------------------------------------------------------------------
__global__ __launch_bounds__(192, 1) void crf_forward(
    const float* __restrict__ em, const float* __restrict__ mask,
    const float* __restrict__ start_t, const float* __restrict__ trans,
    const float* __restrict__ end_t, float* __restrict__ logz)
{
  const int tid  = threadIdx.x;
  const int wid  = tid >> 6;     // 0 consumer, 1 producer-lo, 2 producer-hi
  const int lane = tid & 63;
  const int q    = lane >> 4;    // 0..3
  const int lo   = lane & 15;    // batch row within block
  const int b0   = blockIdx.x * 16;

  __shared__ __align__(16) float Xs[NSLOT][16][XPAD];   // X ring; mask at col 128

  const size_t TS = (size_t)BB * KK;
  const float* emlane = em + (size_t)(b0 + lo) * KK + 4 * q;  // + t*TS + 16*mt
  const float* mrow   = mask + (b0 + lo);                     // + t*BB

  // ---- consumer persistent state
  short8 Af[8][4];
  f4 S[8];
  uint4v PB[4];
  float base = 0.f, mvPrev = 1.0f;

  // ---- producer reg ring (static names — rule #20); 4 f4 per buffer (half tile)
  f4 LA[4], LB[4], LC[4], LD[4];
  float mA = 0.f, mB = 0.f, mC = 0.f, mD = 0.f;
  const int wp  = (wid == 2) ? 1 : 0;     // producer half index
  const int mtb = 4 * wp;                 // mt base (0 or 4)
  const float* emlaneP = emlane + 16 * mtb;

  if (wid == 0) {
    // E fragments, permuted k-mapping: Af[mt][kt][j] = exp(E)[c_k][c_m]
#pragma unroll
    for (int mt = 0; mt < 8; ++mt)
#pragma unroll
      for (int kt = 0; kt < 4; ++kt) {
        short8 v;
#pragma unroll
        for (int j = 0; j < 8; ++j) {
          const int ck = 32 * kt + 16 * (j >> 2) + 4 * q + (j & 3);
          v[j] = (short)f2bf_rtne(__expf(trans[(size_t)ck * KK + 16 * mt + lo]));
        }
        Af[mt][kt] = v;
      }
    // P(0) = exp(start + em(0))
#pragma unroll
    for (int mt = 0; mt < 8; ++mt) {
      const f4 e0 = *(const f4*)(emlane + 16 * mt);
      const f4 st = *(const f4*)(start_t + 16 * mt + 4 * q);
#pragma unroll
      for (int i = 0; i < 4; ++i) S[mt][i] = __expf(st[i] + e0[i]);
    }
#pragma unroll
    for (int kt = 0; kt < 4; ++kt) {
      PB[kt][0] = pack_trunc(S[2 * kt][0],     S[2 * kt][1]);
      PB[kt][1] = pack_trunc(S[2 * kt][2],     S[2 * kt][3]);
      PB[kt][2] = pack_trunc(S[2 * kt + 1][0], S[2 * kt + 1][1]);
      PB[kt][3] = pack_trunc(S[2 * kt + 1][2], S[2 * kt + 1][3]);
    }
  } else {
    // producer prologue loads for t = 1..4 (half tiles)
#pragma unroll
    for (int m = 0; m < 4; ++m) {
      LA[m] = *(const f4*)(emlaneP + 1 * TS + 16 * m);
      LB[m] = *(const f4*)(emlaneP + 2 * TS + 16 * m);
      LC[m] = *(const f4*)(emlaneP + 3 * TS + 16 * m);
      LD[m] = *(const f4*)(emlaneP + 4 * TS + 16 * m);
    }
    if (wp == 0) { mA = mrow[1 * BB]; mB = mrow[2 * BB]; mC = mrow[3 * BB]; mD = mrow[4 * BB]; }
  }

  // produce X(t) half-tile into slot t&7 from buffer Ls, then load t+4
  auto PROD = [&](const int t, f4 (&Ls)[4], float& ms) {
    if (t > TT) return;                       // t in [1..1024]
    float* xb = &Xs[t & 7][lo][0];
#pragma unroll
    for (int m = 0; m < 4; ++m) {
      f4 x;
#pragma unroll
      for (int i = 0; i < 4; ++i) x[i] = __expf(Ls[m][i]);
      *(f4*)(xb + 16 * (mtb + m) + 4 * q) = x;
    }
    if (wp == 0 && q == 0) xb[128] = (t <= TT - 1) ? ms : 0.f;  // dummy: mask 0
    const int tp = (t + 4 <= TT - 1) ? (t + 4) : (TT - 1);
#pragma unroll
    for (int m = 0; m < 4; ++m)
      Ls[m] = *(const f4*)(emlaneP + (size_t)tp * TS + 16 * m);
    if (wp == 0) ms = mrow[(size_t)tp * BB];
  };

  // one recurrence step (r2 verbatim)
  auto CONS = [&](const int t, const bool scale_cand, const bool do_renorm) {
    const float* xb = &Xs[t & 7][lo][0];
    f4 X[8];
#pragma unroll
    for (int mt = 0; mt < 8; ++mt) X[mt] = *(const f4*)(xb + 16 * mt + 4 * q);
    const float mk = xb[128];

    float ps = 1.0f, kln2 = 0.f;
    if (scale_cand) {
      const int k = (int)(__float_as_uint(mvPrev) >> 23) - 127;
      ps = __uint_as_float((unsigned)(127 - k) << 23);
      kln2 = (float)k * 0.6931471805599453f;
    }

    short8 Bf[4];
#pragma unroll
    for (int kt = 0; kt < 4; ++kt) Bf[kt] = __builtin_bit_cast(short8, PB[kt]);

    f4 acc[8];
#pragma unroll
    for (int mt = 0; mt < 8; ++mt) acc[mt] = f4{0.f, 0.f, 0.f, 0.f};
#pragma unroll
    for (int kt = 0; kt < 4; ++kt)
#pragma unroll
      for (int mt = 0; mt < 8; ++mt)
        acc[mt] = __builtin_amdgcn_mfma_f32_16x16x32_bf16(Af[mt][kt], Bf[kt], acc[mt], 0, 0, 0);

    const bool upd = (mk != 0.f);
#pragma unroll
    for (int mt = 0; mt < 8; ++mt)
#pragma unroll
      for (int i = 0; i < 4; ++i) {
        float n = acc[mt][i] * X[mt][i];
        if (scale_cand) n *= ps;
        S[mt][i] = upd ? n : S[mt][i];
      }
    if (scale_cand && upd) base += kln2;

#pragma unroll
    for (int kt = 0; kt < 4; ++kt) {
      PB[kt][0] = pack_trunc(S[2 * kt][0],     S[2 * kt][1]);
      PB[kt][1] = pack_trunc(S[2 * kt][2],     S[2 * kt][3]);
      PB[kt][2] = pack_trunc(S[2 * kt + 1][0], S[2 * kt + 1][1]);
      PB[kt][3] = pack_trunc(S[2 * kt + 1][2], S[2 * kt + 1][3]);
    }

    if (do_renorm) {
      float mv = S[0][0];
#pragma unroll
      for (int mt = 0; mt < 8; ++mt)
#pragma unroll
        for (int i = 0; i < 4; ++i) mv = fmaxf(mv, S[mt][i]);
      mv = fmaxf(mv, __shfl_xor(mv, 16));
      mv = fmaxf(mv, __shfl_xor(mv, 32));
      mvPrev = mv;
    }
  };

  // producer prologue: fill slots 1..4, issue loads t=5..8
  if (wid >= 1) { PROD(1, LA, mA); PROD(2, LB, mB); PROD(3, LC, mC); PROD(4, LD, mD); }
  lgkm_barrier();

  // peeled g=0 (no scale step at t=1)
  if (wid == 0) {
    CONS(1, false, false); CONS(2, false, false);
    CONS(3, false, false); CONS(4, false, true);
  } else {
    PROD(5, LA, mA); PROD(6, LB, mB); PROD(7, LC, mC); PROD(8, LD, mD);
  }
  lgkm_barrier();

  for (int g = 1; g < 256; ++g) {
    const int t0 = 4 * g;
    if (wid == 0) {
      CONS(t0 + 1, true,  false);
      CONS(t0 + 2, false, false);
      CONS(t0 + 3, false, false);
      CONS(t0 + 4, false, true);
    } else {
      PROD(t0 + 5, LA, mA); PROD(t0 + 6, LB, mB);
      PROD(t0 + 7, LC, mC); PROD(t0 + 8, LD, mD);
    }
    lgkm_barrier();
  }

  // ---- finale: logZ[row] = base + log( sum_j P_j * exp(end_j) )
  if (wid == 0) {
    float s = 0.f;
#pragma unroll
    for (int mt = 0; mt < 8; ++mt) {
      const f4 ed = *(const f4*)(end_t + 16 * mt + 4 * q);
#pragma unroll
      for (int i = 0; i < 4; ++i) s += S[mt][i] * __expf(ed[i]);
    }
    s += __shfl_xor(s, 16);
    s += __shfl_xor(s, 32);
    if (q == 0) logz[b0 + lo] = base + logf(s);
  }
}

// ---------------------------------------------------------------------------
// Path score, (t,b)-parallel global sum: block = t, lanes = b (coalesced tags/
// mask; em gather stays inside one 256 KB t-slab -> L2/L3 friendly).
// ---------------------------------------------------------------------------
__global__ __launch_bounds__(512) void crf_path_tb(
    const float* __restrict__ em, const int* __restrict__ tags,
    const float* __restrict__ mask, const float* __restrict__ trans,
    float* __restrict__ ws_tb)
{
  const int t = blockIdx.x, b = threadIdx.x;
  const int tg = tags[t * BB + b];
  const float mk = mask[t * BB + b];
  float v = em[((size_t)t * BB + b) * KK + tg] * mk;
  if (t >= 1) {
    const int tgp = tags[(t - 1) * BB + b];
    v += trans[(size_t)tgp * KK + tg] * mk;
  }
  __shared__ float red[8];
#pragma unroll
  for (int off = 32; off; off >>= 1) v += __shfl_xor(v, off);
  if ((b & 63) == 0) red[b >> 6] = v;
  __syncthreads();
  if (b == 0) {
    float s = 0.f;
#pragma unroll
    for (int i = 0; i < 8; ++i) s += red[i];
    ws_tb[t] = s;
  }
}

// per-b boundary terms: start[tag_0] + end[tag_last] (last from mask sum)
__global__ __launch_bounds__(64) void crf_bterm(
    const int* __restrict__ tags, const float* __restrict__ mask,
    const float* __restrict__ start_t, const float* __restrict__ end_t,
    float* __restrict__ ws_bt)
{
  const int b = blockIdx.x, tid = threadIdx.x;
  float ms = 0.f;
  for (int t = tid; t < TT; t += 64) ms += mask[t * BB + b];
#pragma unroll
  for (int off = 32; off; off >>= 1) ms += __shfl_xor(ms, off);
  if (tid == 0) {
    const int last = (int)(ms + 0.5f) - 1;
    ws_bt[b] = start_t[tags[b]] + end_t[tags[(size_t)last * BB + b]];
  }
}

// out = sum_t ws_tb + sum_b (ws_bt - logz)
__global__ __launch_bounds__(1024) void crf_final(
    const float* __restrict__ ws_tb, const float* __restrict__ ws_bt,
    const float* __restrict__ ws_lz, float* __restrict__ out)
{
  const int tid = threadIdx.x;
  float v = ws_tb[tid];
  if (tid < BB) v += ws_bt[tid] - ws_lz[tid];
  __shared__ float red[16];
#pragma unroll
  for (int off = 32; off; off >>= 1) v += __shfl_xor(v, off);
  if ((tid & 63) == 0) red[tid >> 6] = v;
  __syncthreads();
  if (tid == 0) {
    float s = 0.f;
#pragma unroll
    for (int i = 0; i < 16; ++i) s += red[i];
    out[0] = s;
  }
}

extern "C" void kernel_launch(void* const* d_in, const int* in_sizes, int n_in,
                              void* d_out, int out_size, void* d_ws, size_t ws_size,
                              hipStream_t stream) {
  (void)in_sizes; (void)n_in; (void)out_size; (void)ws_size;
  const float* em    = (const float*)d_in[0];
  const int*   tags  = (const int*)  d_in[1];
  const float* mask  = (const float*)d_in[2];
  const float* st    = (const float*)d_in[3];
  const float* trans = (const float*)d_in[4];
  const float* et    = (const float*)d_in[5];
  float* out = (float*)d_out;

  float* ws_tb = (float*)d_ws;   // [1024]
  float* ws_bt = ws_tb + 1024;   // [512]
  float* ws_lz = ws_bt + 512;    // [512]

  crf_path_tb<<<TT, 512, 0, stream>>>(em, tags, mask, trans, ws_tb);
  crf_bterm  <<<BB, 64, 0, stream>>>(tags, mask, st, et, ws_bt);
  crf_forward<<<32, 192, 0, stream>>>(em, mask, st, trans, et, ws_lz);
  crf_final  <<<1, 1024, 0, stream>>>(ws_tb, ws_bt, ws_lz, out);
}